// Round 2
// baseline (291.859 us; speedup 1.0000x reference)
//
#include <hip/hip_runtime.h>
#include <hip/hip_bf16.h>

typedef __bf16 bf16x8_t __attribute__((ext_vector_type(8)));
typedef __bf16 bf16x4_t __attribute__((ext_vector_type(4)));
typedef float  f32x4_t  __attribute__((ext_vector_type(4)));

#define MFMA_16x16x32_BF16(A, B, C) __builtin_amdgcn_mfma_f32_16x16x32_bf16((A), (B), (C), 0, 0, 0)

static constexpr int B_ = 16;
static constexpr int T_ = 2048;
static constexpr int C_ = 1024;
static constexpr int H_ = 128;
static constexpr long M_ = (long)B_ * T_;   // 32768 rows

__device__ __forceinline__ void gload_lds16(const void* g, void* l)
{
    __builtin_amdgcn_global_load_lds(
        (const __attribute__((address_space(1))) void*)g,
        (__attribute__((address_space(3))) void*)l, 16, 0, 0);
}

// ---------------------------------------------------------------------------
// W transpose: WT[z][h][c] = bf16(W_z[c][h]).  Flat: WT[n][c], n = z*128+h.
// ---------------------------------------------------------------------------
__global__ __launch_bounds__(128) void wt_kernel(
    const float* __restrict__ Wq, const float* __restrict__ Wk,
    const float* __restrict__ Wv, __bf16* __restrict__ WT)
{
    const int z = blockIdx.y;
    const float* __restrict__ W = (z == 0) ? Wq : (z == 1) ? Wk : Wv;
    const int h  = threadIdx.x;
    const int c0 = blockIdx.x * 8;
    bf16x8_t v;
    #pragma unroll
    for (int j = 0; j < 8; ++j)
        v[j] = (__bf16)W[(c0 + j) * H_ + h];
    *(bf16x8_t*)&WT[((long)z * H_ + h) * C_ + c0] = v;
}

// ---------------------------------------------------------------------------
// Fused projection, v2: 512 threads / 8 waves per block, 64 rows x 384 cols.
// Wave w: m-tile (w>>1), n-half (w&1) -> 12 acc tiles (48 VGPR).
// Double-buffered unpadded LDS (XS[2][64][32] 8 KB + WS[2][384][32] 48 KB):
// unpadded 64 B row stride makes every MFMA fragment subtile a contiguous
// 1 KB block -> conflict-free ds_read_b128, and global_load_lds-compatible.
// W staged via global_load_lds width=16 (3 wave-instr/wave/k-step, no VGPR
// round-trip); x staged via f32x4->bf16 with issue-early/write-late split.
// One __syncthreads per k-step; prefetch latency hides under 12 MFMAs.
// Grid 512, 2 blocks/CU (LDS 56 KB), 16 waves/CU.
// ---------------------------------------------------------------------------
__global__ __launch_bounds__(512, 4) void proj_kernel(
    const float*  __restrict__ x,
    const __bf16* __restrict__ WT,
    __bf16* __restrict__ qo,
    __bf16* __restrict__ ko,
    __bf16* __restrict__ vo)
{
    __shared__ __bf16 XS[2][64 * 32];    //  8 KB
    __shared__ __bf16 WS[2][384 * 32];   // 48 KB

    const int tid  = threadIdx.x;
    const int w    = tid >> 6;
    const int lane = tid & 63;
    const int m16  = lane & 15;
    const int quad = lane >> 4;
    const int koff = quad * 8;
    const int mt   = w >> 1;             // m-tile 0..3
    const int nh   = w & 1;              // n-half 0..1

    const long r0 = (long)blockIdx.x * 64;

    // staging coords
    const int xrow = tid >> 3, xc = tid & 7;          // x: one f32x4 / thread
    const int wrow = lane >> 2, wcol = lane & 3;      // W: gload_lds lane map

    f32x4_t acc[12];
    #pragma unroll
    for (int j = 0; j < 12; ++j) acc[j] = f32x4_t{0, 0, 0, 0};

    // ---- prologue: stage k-step 0 into buffer 0 ----
    {
        f32x4_t xv = *(const f32x4_t*)&x[(r0 + xrow) * C_ + xc * 4];
        #pragma unroll
        for (int ch = 0; ch < 3; ++ch) {
            const int rowb = w * 48 + ch * 16;
            gload_lds16(&WT[(long)(rowb + wrow) * C_ + wcol * 8],
                        &WS[0][rowb * 32]);
        }
        bf16x4_t xb;
        #pragma unroll
        for (int j = 0; j < 4; ++j) xb[j] = (__bf16)xv[j];
        *(bf16x4_t*)&XS[0][xrow * 32 + xc * 4] = xb;
    }
    __syncthreads();

    for (int t = 0; t < 32; ++t) {
        const int cur = t & 1, nxt = cur ^ 1;
        const int k0n = (t + 1) * 32;

        // issue next tile's loads first (latency hides under MFMAs)
        f32x4_t xv;
        if (t < 31) {
            xv = *(const f32x4_t*)&x[(r0 + xrow) * C_ + k0n + xc * 4];
            #pragma unroll
            for (int ch = 0; ch < 3; ++ch) {
                const int rowb = w * 48 + ch * 16;
                gload_lds16(&WT[(long)(rowb + wrow) * C_ + k0n + wcol * 8],
                            &WS[nxt][rowb * 32]);
            }
        }

        // compute current tile
        bf16x8_t a = *(const bf16x8_t*)&XS[cur][(mt * 16 + m16) * 32 + koff];
        #pragma unroll
        for (int j = 0; j < 12; ++j) {
            bf16x8_t bfr =
                *(const bf16x8_t*)&WS[cur][((nh * 12 + j) * 16 + m16) * 32 + koff];
            acc[j] = MFMA_16x16x32_BF16(a, bfr, acc[j]);
        }

        // write-late x staging for next tile
        if (t < 31) {
            bf16x4_t xb;
            #pragma unroll
            for (int j = 0; j < 4; ++j) xb[j] = (__bf16)xv[j];
            *(bf16x4_t*)&XS[nxt][xrow * 32 + xc * 4] = xb;
        }
        __syncthreads();   // drains vmcnt (gload_lds) + lgkm once per k-step
    }

    // Epilogue. C/D: col = m16 (n), row = quad*4 + r (m).
    const long rbase = r0 + mt * 16 + quad * 4;
    #pragma unroll
    for (int j = 0; j < 12; ++j) {
        const int ntg = nh * 12 + j;
        const int z = ntg >> 3;
        const int h = (ntg & 7) * 16 + m16;
        if (z < 2) {
            __bf16* __restrict__ o = z ? ko : qo;
            #pragma unroll
            for (int r = 0; r < 4; ++r)
                o[(rbase + r) * H_ + h] = (__bf16)acc[j][r];
        } else {
            long bb = rbase >> 11, tt = rbase & 2047;   // 64 | 2048: rows stay in batch
            bf16x4_t pk;
            #pragma unroll
            for (int r = 0; r < 4; ++r) pk[r] = (__bf16)acc[j][r];
            *(bf16x4_t*)&vo[bb * (H_ * (long)T_) + h * (long)T_ + tt] = pk;
        }
    }
}

// ---------------------------------------------------------------------------
// Flash attention, causal, transposed-score, LDS-SHARED K/V tiles.
// Block = 4 waves x 16 q-rows = 64 q-rows; one shared k-sweep in 64-wide
// tiles staged in LDS (K [64][136] pad, V^T [128][72] pad). Wave w owns
// q-tile qb*64 + w*16 fully -> no merge. Masked tail iterations for early
// waves are numerically no-ops (p=0, al=1).
// Grid 512 1-D: linear%16 = batch (XCD-pins K/V: batch b -> XCD b%8, 2 MB L2
// resident); qb decode pairs heavy+light blocks per CU (sums = 31 sweeps).
// ---------------------------------------------------------------------------
__global__ __launch_bounds__(256) void attn_kernel(
    const __bf16* __restrict__ q,   // [B][T][H]
    const __bf16* __restrict__ k,   // [B][T][H]
    const __bf16* __restrict__ vT,  // [B][H][T]
    float* __restrict__ out)        // [B][T][H] fp32
{
    __shared__ __bf16 KS[64 * 136];     // [krow][h], pad 8  (17.4 KB)
    __shared__ __bf16 VS[128 * 72];     // [h][t],    pad 8  (18.4 KB)
    __shared__ __bf16 PS[4][16 * 72];   // per-wave P [q][k], pad 8 (9.2 KB)

    const int L   = blockIdx.x;
    const int b   = L & 15;
    const int Lh  = L >> 4;                       // 0..31
    const int qb  = (Lh < 16) ? (31 - Lh) : (Lh - 16);   // heavy first, CU-paired

    const int tid  = threadIdx.x;
    const int w    = tid >> 6;
    const int lane = tid & 63;
    const int m16  = lane & 15;
    const int quad = lane >> 4;
    const int koff = quad * 8;

    const __bf16* __restrict__ qp = q  + (long)b * T_ * H_;
    const __bf16* __restrict__ kp = k  + (long)b * T_ * H_;
    const __bf16* __restrict__ vp = vT + (long)b * H_ * T_;

    const int q0w = qb * 64 + w * 16;             // wave's q-tile base
    const int qg  = q0w + m16;                    // this lane's q row

    // Q^T B-fragments (lane n=m16=q, k=h)
    bf16x8_t qfr[4];
    #pragma unroll
    for (int s = 0; s < 4; ++s)
        qfr[s] = *(const bf16x8_t*)&qp[(q0w + m16) * H_ + s * 32 + koff];

    f32x4_t acc[8];                               // O^T: row=h, col=q
    #pragma unroll
    for (int i = 0; i < 8; ++i) acc[i] = f32x4_t{0, 0, 0, 0};
    float mrun = -1e30f, lrun = 0.f;

    __bf16* Pb = &PS[w][0];
    const float SC = 0.08838834764831845f;        // 1/sqrt(128)
    const int kend = qb * 64 + 64;

    // staging coords
    const int krow = tid >> 4, kc16 = tid & 15;   // K: 16 thr/row (256B)
    const int vrow = tid >> 3, vc8  = tid & 7;    // V: 8 thr/row (128B)

    for (int tk0 = 0; tk0 < kend; tk0 += 64) {
        __syncthreads();                          // prev compute done
        #pragma unroll
        for (int ch = 0; ch < 4; ++ch) {
            int r = krow + ch * 16;
            *(bf16x8_t*)&KS[r * 136 + kc16 * 8] =
                *(const bf16x8_t*)&kp[(tk0 + r) * H_ + kc16 * 8];
        }
        #pragma unroll
        for (int ch = 0; ch < 4; ++ch) {
            int hh = vrow + ch * 32;
            *(bf16x8_t*)&VS[hh * 72 + vc8 * 8] =
                *(const bf16x8_t*)&vp[hh * (long)T_ + tk0 + vc8 * 8];
        }
        __syncthreads();                          // tiles ready

        // ---- S^T = K Q^T : 4 S-tiles of 16 k-rows ----
        f32x4_t st[4];
        #pragma unroll
        for (int kt = 0; kt < 4; ++kt) {
            f32x4_t s = f32x4_t{0, 0, 0, 0};
            #pragma unroll
            for (int sI = 0; sI < 4; ++sI) {
                bf16x8_t kf = *(const bf16x8_t*)&KS[(kt * 16 + m16) * 136 + sI * 32 + koff];
                s = MFMA_16x16x32_BF16(kf, qfr[sI], s);
            }
            st[kt] = s;
        }

        // ---- scale (+ causal mask only on boundary tiles, wave-uniform) ----
        float vv[4][4];
        if (tk0 + 63 <= q0w) {                    // fully unmasked
            #pragma unroll
            for (int kt = 0; kt < 4; ++kt)
                #pragma unroll
                for (int r = 0; r < 4; ++r)
                    vv[kt][r] = st[kt][r] * SC;
        } else {
            #pragma unroll
            for (int kt = 0; kt < 4; ++kt)
                #pragma unroll
                for (int r = 0; r < 4; ++r) {
                    int kg = tk0 + kt * 16 + quad * 4 + r;
                    vv[kt][r] = (kg <= qg) ? st[kt][r] * SC : -1e30f;
                }
        }

        float mloc = -1e30f;
        #pragma unroll
        for (int kt = 0; kt < 4; ++kt)
            #pragma unroll
            for (int r = 0; r < 4; ++r)
                mloc = fmaxf(mloc, vv[kt][r]);
        mloc = fmaxf(mloc, __shfl_xor(mloc, 16, 64));
        mloc = fmaxf(mloc, __shfl_xor(mloc, 32, 64));

        float mnew = fmaxf(mrun, mloc);
        float al   = __expf(mrun - mnew);
        float psum = 0.f;
        #pragma unroll
        for (int kt = 0; kt < 4; ++kt) {
            bf16x4_t pk;
            #pragma unroll
            for (int r = 0; r < 4; ++r) {
                float p = __expf(vv[kt][r] - mnew);
                psum += p;
                pk[r] = (__bf16)p;
            }
            *(bf16x4_t*)&Pb[m16 * 72 + kt * 16 + quad * 4] = pk;
        }
        psum += __shfl_xor(psum, 16, 64);
        psum += __shfl_xor(psum, 32, 64);
        mrun = mnew;
        lrun = lrun * al + psum;

        #pragma unroll
        for (int i = 0; i < 8; ++i)
            #pragma unroll
            for (int r = 0; r < 4; ++r)
                acc[i][r] *= al;

        // ---- O^T += V^T P^T : two K=32 halves over the 64-wide tile ----
        #pragma unroll
        for (int half = 0; half < 2; ++half) {
            bf16x8_t pa = *(const bf16x8_t*)&Pb[m16 * 72 + half * 32 + koff];
            #pragma unroll
            for (int i = 0; i < 8; ++i) {
                bf16x8_t vf = *(const bf16x8_t*)&VS[(i * 16 + m16) * 72 + half * 32 + koff];
                acc[i] = MFMA_16x16x32_BF16(vf, pa, acc[i]);
            }
        }
    }

    // ---- epilogue: O[q][h] = acc/lrun, f32x4 stores ----
    float* __restrict__ ob = out + (long)b * T_ * H_;
    const float inv = 1.f / lrun;
    #pragma unroll
    for (int i = 0; i < 8; ++i) {
        f32x4_t o;
        #pragma unroll
        for (int r = 0; r < 4; ++r) o[r] = acc[i][r] * inv;
        *(f32x4_t*)&ob[(q0w + m16) * H_ + i * 16 + quad * 4] = o;
    }
}

// ---------------------------------------------------------------------------
extern "C" void kernel_launch(void* const* d_in, const int* in_sizes, int n_in,
                              void* d_out, int out_size, void* d_ws, size_t ws_size,
                              hipStream_t stream)
{
    // setup_inputs order: x, Wk, Wq, Wv — all float32
    const float* x  = (const float*)d_in[0];
    const float* Wk = (const float*)d_in[1];
    const float* Wq = (const float*)d_in[2];
    const float* Wv = (const float*)d_in[3];

    // ws: q [M,H] bf16 | k [M,H] bf16 | vT [B][H][T] bf16 | WT [3][H][C] bf16
    __bf16* qws = (__bf16*)d_ws;
    __bf16* kws = qws + M_ * H_;
    __bf16* vws = kws + M_ * H_;
    __bf16* WT  = vws + (long)B_ * H_ * T_;
    float*  out = (float*)d_out;

    wt_kernel  <<<dim3(C_ / 8, 3), 128, 0, stream>>>(Wq, Wk, Wv, WT);
    proj_kernel<<<dim3((int)(M_ / 64)), 512, 0, stream>>>(x, WT, qws, kws, vws);
    attn_kernel<<<dim3(512), 256, 0, stream>>>(qws, kws, vws, out);
}

// Round 3
// 290.631 us; speedup vs baseline: 1.0042x; 1.0042x over previous
//
#include <hip/hip_runtime.h>
#include <hip/hip_bf16.h>

typedef __bf16 bf16x8_t __attribute__((ext_vector_type(8)));
typedef __bf16 bf16x4_t __attribute__((ext_vector_type(4)));
typedef float  f32x4_t  __attribute__((ext_vector_type(4)));

#define MFMA_16x16x32_BF16(A, B, C) __builtin_amdgcn_mfma_f32_16x16x32_bf16((A), (B), (C), 0, 0, 0)

static constexpr int B_ = 16;
static constexpr int T_ = 2048;
static constexpr int C_ = 1024;
static constexpr int H_ = 128;
static constexpr long M_ = (long)B_ * T_;   // 32768 rows

__device__ __forceinline__ void gload_lds16(const void* g, void* l)
{
    __builtin_amdgcn_global_load_lds(
        (const __attribute__((address_space(1))) void*)g,
        (__attribute__((address_space(3))) void*)l, 16, 0, 0);
}

// ---------------------------------------------------------------------------
// W transpose: WT[z][h][c] = bf16(W_z[c][h]).  Flat: WT[n][c], n = z*128+h.
// ---------------------------------------------------------------------------
__global__ __launch_bounds__(128) void wt_kernel(
    const float* __restrict__ Wq, const float* __restrict__ Wk,
    const float* __restrict__ Wv, __bf16* __restrict__ WT)
{
    const int z = blockIdx.y;
    const float* __restrict__ W = (z == 0) ? Wq : (z == 1) ? Wk : Wv;
    const int h  = threadIdx.x;
    const int c0 = blockIdx.x * 8;
    bf16x8_t v;
    #pragma unroll
    for (int j = 0; j < 8; ++j)
        v[j] = (__bf16)W[(c0 + j) * H_ + h];
    *(bf16x8_t*)&WT[((long)z * H_ + h) * C_ + c0] = v;
}

// ---------------------------------------------------------------------------
// Fused projection, v3: 512 thr / 8 waves, 64 rows x 384 cols per block.
// Wave w: rows mt2*32..+31 (mt2=w>>2), n-subtiles nq*6..+5 (nq=w&3):
// 2 a-frags x 6 b-frags = 12 MFMA/step, b reused x2 (halves LDS b-traffic).
// ALL staging via global_load_lds (x staged as fp32, cvt at frag build).
// XOR-swizzled both-sides (rule #21): source global addr pre-swizzled,
// read addr same XOR; LDS linear. W: qc ^= (row>>1)&3 -> fragment reads
// 2-way (free). x: unit ^= row&7 -> 2-way.
// Counted vmcnt (T4): s_barrier + s_waitcnt vmcnt(4) -> next step's 4 loads
// stay in flight across the barrier; never drain to 0 in the loop.
// LDS 64 KB (XS f32 2x8K + WS 2x24K) -> 2 blocks/CU, 16 waves/CU.
// ---------------------------------------------------------------------------
__global__ __launch_bounds__(512, 4) void proj_kernel(
    const float*  __restrict__ x,
    const __bf16* __restrict__ WT,
    __bf16* __restrict__ qo,
    __bf16* __restrict__ ko,
    __bf16* __restrict__ vo)
{
    __shared__ float  XS[2][64 * 32];    // fp32 x tile, 8 KB each
    __shared__ __bf16 WS[2][384 * 32];   // bf16 W tile, 24 KB each

    const int tid  = threadIdx.x;
    const int w    = tid >> 6;
    const int lane = tid & 63;
    const int m16  = lane & 15;
    const int quad = lane >> 4;
    const int mt2  = w >> 2;             // row-half 0..1 (32 rows)
    const int nq   = w & 3;              // n-quarter 0..3 (6 subtiles)

    const long r0 = (long)blockIdx.x * 64;

    // staging source swizzles (pre-swizzled global, linear LDS — rule #21)
    const int xrow = tid >> 3;                           // 0..63
    const int xcol = ((tid & 7) ^ (xrow & 7)) << 2;      // f32 col, unit^row&7
    const int wrr  = lane >> 2;                          // 0..15 within chunk
    const int wqc  = ((lane & 3) ^ ((lane >> 3) & 3)) << 3;  // bf16 col

    f32x4_t acc[2][6];
    #pragma unroll
    for (int hh = 0; hh < 2; ++hh)
        #pragma unroll
        for (int j = 0; j < 6; ++j) acc[hh][j] = f32x4_t{0, 0, 0, 0};

    // ---- prologue: stage k-step 0 into buffer 0 (4 gload_lds / thread) ----
    gload_lds16(&x[(r0 + xrow) * C_ + xcol], &XS[0][w * 8 * 32]);
    #pragma unroll
    for (int ch = 0; ch < 3; ++ch) {
        const int rowb = w * 48 + ch * 16;
        gload_lds16(&WT[(long)(rowb + wrr) * C_ + wqc], &WS[0][rowb * 32]);
    }

    for (int t = 0; t < 32; ++t) {
        const int cur = t & 1, nxt = cur ^ 1;
        const int k0n = (t + 1) * 32;

        // issue next tile's 4 loads, then wait only for the PREVIOUS 4
        if (t < 31) {
            gload_lds16(&x[(r0 + xrow) * C_ + k0n + xcol], &XS[nxt][w * 8 * 32]);
            #pragma unroll
            for (int ch = 0; ch < 3; ++ch) {
                const int rowb = w * 48 + ch * 16;
                gload_lds16(&WT[(long)(rowb + wrr) * C_ + k0n + wqc],
                            &WS[nxt][rowb * 32]);
            }
            __builtin_amdgcn_sched_barrier(0);
            asm volatile("s_waitcnt vmcnt(4)" ::: "memory");
        } else {
            __builtin_amdgcn_sched_barrier(0);
            asm volatile("s_waitcnt vmcnt(0)" ::: "memory");
        }
        __builtin_amdgcn_s_barrier();          // buf[cur] staged by all waves
        __builtin_amdgcn_sched_barrier(0);

        // a-frags: fp32 -> bf16, swizzled read (unit = (quad*2+r) ^ (row&7))
        bf16x8_t a[2];
        #pragma unroll
        for (int hh = 0; hh < 2; ++hh) {
            const int row = mt2 * 32 + hh * 16 + m16;
            const int sw  = m16 & 7;
            f32x4_t lo = *(const f32x4_t*)&XS[cur][row * 32 + (((quad * 2 + 0) ^ sw) << 2)];
            f32x4_t hi = *(const f32x4_t*)&XS[cur][row * 32 + (((quad * 2 + 1) ^ sw) << 2)];
            #pragma unroll
            for (int jj = 0; jj < 4; ++jj) {
                a[hh][jj]     = (__bf16)lo[jj];
                a[hh][4 + jj] = (__bf16)hi[jj];
            }
        }
        // b-frags: swizzled read (qc = quad ^ ((row>>1)&3)), reused x2
        const int qsw = (quad ^ ((m16 >> 1) & 3)) << 3;
        #pragma unroll
        for (int j = 0; j < 6; ++j) {
            const int row = (nq * 6 + j) * 16 + m16;
            bf16x8_t b = *(const bf16x8_t*)&WS[cur][row * 32 + qsw];
            acc[0][j] = MFMA_16x16x32_BF16(a[0], b, acc[0][j]);
            acc[1][j] = MFMA_16x16x32_BF16(a[1], b, acc[1][j]);
        }

        __builtin_amdgcn_sched_barrier(0);
        asm volatile("s_waitcnt lgkmcnt(0)" ::: "memory");
        __builtin_amdgcn_s_barrier();          // reads done -> buf[cur] reusable
        __builtin_amdgcn_sched_barrier(0);
    }

    // Epilogue. C/D: col = m16 (n), row = quad*4 + r (m).
    #pragma unroll
    for (int hh = 0; hh < 2; ++hh) {
        const long rbase = r0 + mt2 * 32 + hh * 16 + quad * 4;
        #pragma unroll
        for (int j = 0; j < 6; ++j) {
            const int nt = nq * 6 + j;
            const int z  = nt >> 3;
            const int h  = (nt & 7) * 16 + m16;
            if (z < 2) {
                __bf16* __restrict__ o = z ? ko : qo;
                #pragma unroll
                for (int r = 0; r < 4; ++r)
                    o[(rbase + r) * H_ + h] = (__bf16)acc[hh][j][r];
            } else {
                long bb = rbase >> 11, tt = rbase & 2047;  // rows stay in batch
                bf16x4_t pk;
                #pragma unroll
                for (int r = 0; r < 4; ++r) pk[r] = (__bf16)acc[hh][j][r];
                *(bf16x4_t*)&vo[bb * (H_ * (long)T_) + h * (long)T_ + tt] = pk;
            }
        }
    }
}

// ---------------------------------------------------------------------------
// Flash attention, causal, transposed-score, LDS-SHARED K/V tiles.
// (unchanged from the 275 µs baseline)
// ---------------------------------------------------------------------------
__global__ __launch_bounds__(256) void attn_kernel(
    const __bf16* __restrict__ q,   // [B][T][H]
    const __bf16* __restrict__ k,   // [B][T][H]
    const __bf16* __restrict__ vT,  // [B][H][T]
    float* __restrict__ out)        // [B][T][H] fp32
{
    __shared__ __bf16 KS[64 * 136];     // [krow][h], pad 8  (17.4 KB)
    __shared__ __bf16 VS[128 * 72];     // [h][t],    pad 8  (18.4 KB)
    __shared__ __bf16 PS[4][16 * 72];   // per-wave P [q][k], pad 8 (9.2 KB)

    const int L   = blockIdx.x;
    const int b   = L & 15;
    const int Lh  = L >> 4;                       // 0..31
    const int qb  = (Lh < 16) ? (31 - Lh) : (Lh - 16);   // heavy first, CU-paired

    const int tid  = threadIdx.x;
    const int w    = tid >> 6;
    const int lane = tid & 63;
    const int m16  = lane & 15;
    const int quad = lane >> 4;
    const int koff = quad * 8;

    const __bf16* __restrict__ qp = q  + (long)b * T_ * H_;
    const __bf16* __restrict__ kp = k  + (long)b * T_ * H_;
    const __bf16* __restrict__ vp = vT + (long)b * H_ * T_;

    const int q0w = qb * 64 + w * 16;             // wave's q-tile base
    const int qg  = q0w + m16;                    // this lane's q row

    // Q^T B-fragments (lane n=m16=q, k=h)
    bf16x8_t qfr[4];
    #pragma unroll
    for (int s = 0; s < 4; ++s)
        qfr[s] = *(const bf16x8_t*)&qp[(q0w + m16) * H_ + s * 32 + koff];

    f32x4_t acc[8];                               // O^T: row=h, col=q
    #pragma unroll
    for (int i = 0; i < 8; ++i) acc[i] = f32x4_t{0, 0, 0, 0};
    float mrun = -1e30f, lrun = 0.f;

    __bf16* Pb = &PS[w][0];
    const float SC = 0.08838834764831845f;        // 1/sqrt(128)
    const int kend = qb * 64 + 64;

    // staging coords
    const int krow = tid >> 4, kc16 = tid & 15;   // K: 16 thr/row (256B)
    const int vrow = tid >> 3, vc8  = tid & 7;    // V: 8 thr/row (128B)

    for (int tk0 = 0; tk0 < kend; tk0 += 64) {
        __syncthreads();                          // prev compute done
        #pragma unroll
        for (int ch = 0; ch < 4; ++ch) {
            int r = krow + ch * 16;
            *(bf16x8_t*)&KS[r * 136 + kc16 * 8] =
                *(const bf16x8_t*)&kp[(tk0 + r) * H_ + kc16 * 8];
        }
        #pragma unroll
        for (int ch = 0; ch < 4; ++ch) {
            int hh = vrow + ch * 32;
            *(bf16x8_t*)&VS[hh * 72 + vc8 * 8] =
                *(const bf16x8_t*)&vp[hh * (long)T_ + tk0 + vc8 * 8];
        }
        __syncthreads();                          // tiles ready

        // ---- S^T = K Q^T : 4 S-tiles of 16 k-rows ----
        f32x4_t st[4];
        #pragma unroll
        for (int kt = 0; kt < 4; ++kt) {
            f32x4_t s = f32x4_t{0, 0, 0, 0};
            #pragma unroll
            for (int sI = 0; sI < 4; ++sI) {
                bf16x8_t kf = *(const bf16x8_t*)&KS[(kt * 16 + m16) * 136 + sI * 32 + koff];
                s = MFMA_16x16x32_BF16(kf, qfr[sI], s);
            }
            st[kt] = s;
        }

        // ---- scale (+ causal mask only on boundary tiles, wave-uniform) ----
        float vv[4][4];
        if (tk0 + 63 <= q0w) {                    // fully unmasked
            #pragma unroll
            for (int kt = 0; kt < 4; ++kt)
                #pragma unroll
                for (int r = 0; r < 4; ++r)
                    vv[kt][r] = st[kt][r] * SC;
        } else {
            #pragma unroll
            for (int kt = 0; kt < 4; ++kt)
                #pragma unroll
                for (int r = 0; r < 4; ++r) {
                    int kg = tk0 + kt * 16 + quad * 4 + r;
                    vv[kt][r] = (kg <= qg) ? st[kt][r] * SC : -1e30f;
                }
        }

        float mloc = -1e30f;
        #pragma unroll
        for (int kt = 0; kt < 4; ++kt)
            #pragma unroll
            for (int r = 0; r < 4; ++r)
                mloc = fmaxf(mloc, vv[kt][r]);
        mloc = fmaxf(mloc, __shfl_xor(mloc, 16, 64));
        mloc = fmaxf(mloc, __shfl_xor(mloc, 32, 64));

        float mnew = fmaxf(mrun, mloc);
        float al   = __expf(mrun - mnew);
        float psum = 0.f;
        #pragma unroll
        for (int kt = 0; kt < 4; ++kt) {
            bf16x4_t pk;
            #pragma unroll
            for (int r = 0; r < 4; ++r) {
                float p = __expf(vv[kt][r] - mnew);
                psum += p;
                pk[r] = (__bf16)p;
            }
            *(bf16x4_t*)&Pb[m16 * 72 + kt * 16 + quad * 4] = pk;
        }
        psum += __shfl_xor(psum, 16, 64);
        psum += __shfl_xor(psum, 32, 64);
        mrun = mnew;
        lrun = lrun * al + psum;

        #pragma unroll
        for (int i = 0; i < 8; ++i)
            #pragma unroll
            for (int r = 0; r < 4; ++r)
                acc[i][r] *= al;

        // ---- O^T += V^T P^T : two K=32 halves over the 64-wide tile ----
        #pragma unroll
        for (int half = 0; half < 2; ++half) {
            bf16x8_t pa = *(const bf16x8_t*)&Pb[m16 * 72 + half * 32 + koff];
            #pragma unroll
            for (int i = 0; i < 8; ++i) {
                bf16x8_t vf = *(const bf16x8_t*)&VS[(i * 16 + m16) * 72 + half * 32 + koff];
                acc[i] = MFMA_16x16x32_BF16(vf, pa, acc[i]);
            }
        }
    }

    // ---- epilogue: O[q][h] = acc/lrun, f32x4 stores ----
    float* __restrict__ ob = out + (long)b * T_ * H_;
    const float inv = 1.f / lrun;
    #pragma unroll
    for (int i = 0; i < 8; ++i) {
        f32x4_t o;
        #pragma unroll
        for (int r = 0; r < 4; ++r) o[r] = acc[i][r] * inv;
        *(f32x4_t*)&ob[(q0w + m16) * H_ + i * 16 + quad * 4] = o;
    }
}

// ---------------------------------------------------------------------------
extern "C" void kernel_launch(void* const* d_in, const int* in_sizes, int n_in,
                              void* d_out, int out_size, void* d_ws, size_t ws_size,
                              hipStream_t stream)
{
    // setup_inputs order: x, Wk, Wq, Wv — all float32
    const float* x  = (const float*)d_in[0];
    const float* Wk = (const float*)d_in[1];
    const float* Wq = (const float*)d_in[2];
    const float* Wv = (const float*)d_in[3];

    // ws: q [M,H] bf16 | k [M,H] bf16 | vT [B][H][T] bf16 | WT [3][H][C] bf16
    __bf16* qws = (__bf16*)d_ws;
    __bf16* kws = qws + M_ * H_;
    __bf16* vws = kws + M_ * H_;
    __bf16* WT  = vws + (long)B_ * H_ * T_;
    float*  out = (float*)d_out;

    wt_kernel  <<<dim3(C_ / 8, 3), 128, 0, stream>>>(Wq, Wk, Wv, WT);
    proj_kernel<<<dim3((int)(M_ / 64)), 512, 0, stream>>>(x, WT, qws, kws, vws);
    attn_kernel<<<dim3(512), 256, 0, stream>>>(qws, kws, vws, out);
}